// Round 8
// baseline (354.538 us; speedup 1.0000x reference)
//
#include <hip/hip_runtime.h>
#include <hip/hip_bf16.h>

typedef __attribute__((ext_vector_type(8))) short bf16x8;
typedef __attribute__((ext_vector_type(4))) float f32x4;
typedef __attribute__((ext_vector_type(4))) short short4_t;
typedef __attribute__((ext_vector_type(8))) short short8_t;
typedef __attribute__((ext_vector_type(4))) float float4_t;

#define MFMA16(a, b, c) __builtin_amdgcn_mfma_f32_16x16x32_bf16((a), (b), (c), 0, 0, 0)

__device__ __forceinline__ unsigned short f2bf(float f) {
    unsigned u = __builtin_bit_cast(unsigned, f);
    u += 0x7fffu + ((u >> 16) & 1u);   // round-to-nearest-even
    return (unsigned short)(u >> 16);
}

__device__ __forceinline__ short4_t pack4(float4_t v) {
    short4_t r;
    r[0] = (short)f2bf(v[0]);
    r[1] = (short)f2bf(v[1]);
    r[2] = (short)f2bf(v[2]);
    r[3] = (short)f2bf(v[3]);
    return r;
}

// async global->LDS, 16B per lane. LDS dest is wave-uniform base + lane*16.
__device__ __forceinline__ void gload_lds16(const void* g, void* l) {
    __builtin_amdgcn_global_load_lds(
        (const __attribute__((address_space(1))) unsigned int*)g,
        (__attribute__((address_space(3))) unsigned int*)l, 16, 0, 0);
}

// Counted-vmcnt barrier (T4): keep the newest N VMEM ops in flight across the
// barrier instead of __syncthreads' full vmcnt(0) drain. lgkmcnt(0) publishes
// LDS writes. sched_barrier stops reordering around the inline asm.
#define BARRIER_VM(N)                                                        \
    do {                                                                     \
        asm volatile("s_waitcnt vmcnt(" #N ") lgkmcnt(0)" ::: "memory");     \
        __builtin_amdgcn_sched_barrier(0);                                   \
        __builtin_amdgcn_s_barrier();                                        \
    } while (0)

// ---------------------------------------------------------------------------
// cast: f32 -> bf16 for support (8.4M), queries (8.4M), Wq/Wk/Wv (0.5M each).
// ---------------------------------------------------------------------------
__global__ __launch_bounds__(256) void cast_kernel(
    const float* __restrict__ support, const float* __restrict__ queries,
    const float* __restrict__ Wq, const float* __restrict__ Wk,
    const float* __restrict__ Wv,
    unsigned short* __restrict__ sb, unsigned short* __restrict__ qb,
    unsigned short* __restrict__ wqb, unsigned short* __restrict__ wkb,
    unsigned short* __restrict__ wvb)
{
    const size_t e = ((size_t)blockIdx.x * 256 + threadIdx.x) * 8;
    const float* src; unsigned short* dst; size_t off;
    if (e < 8388608)       { src = support; dst = sb;  off = e; }
    else if (e < 16777216) { src = queries; dst = qb;  off = e - 8388608; }
    else if (e < 17301504) { src = Wq;      dst = wqb; off = e - 16777216; }
    else if (e < 17825792) { src = Wk;      dst = wkb; off = e - 17301504; }
    else                   { src = Wv;      dst = wvb; off = e - 17825792; }
    float4_t a = *(const float4_t*)(src + off);
    float4_t b = *(const float4_t*)(src + off + 4);
    short4_t lo = pack4(a), hi = pack4(b);
    short8_t o;
    o[0] = lo[0]; o[1] = lo[1]; o[2] = lo[2]; o[3] = lo[3];
    o[4] = hi[0]; o[5] = hi[1]; o[6] = hi[2]; o[7] = hi[3];
    *(short8_t*)(dst + off) = o;
}

// ---------------------------------------------------------------------------
// proj_v: out = in @ Wv^T + bv, modes {0: queries->q_proto f32, 1: support->
// VsT bf16 transposed}. bf16 inputs, global_load_lds staging (XOR-preswizzle).
// ---------------------------------------------------------------------------
__global__ __launch_bounds__(512, 2) void proj_v_kernel(
    const unsigned short* __restrict__ sb, const unsigned short* __restrict__ qb,
    const unsigned short* __restrict__ wvb, const float* __restrict__ bv,
    float* __restrict__ q_proto, unsigned short* __restrict__ VsT)
{
    const int mode = blockIdx.x >> 7;
    const int rem = blockIdx.x & 127;
    const int rowbase = (rem >> 1) * 128;
    const int colbase = (rem & 1) * 256;
    const unsigned short* A = mode ? sb : qb;

    const int t = threadIdx.x;
    const int w = t >> 6, l = t & 63, lg = l >> 4, ll = l & 15;
    const int wr = w & 1, wc = w >> 1;
    const int sr = l >> 3, su = l & 7;

    __shared__ unsigned short Alds[2][128][64];
    __shared__ unsigned short Blds[2][256][64];

    f32x4 acc[4][4];
    #pragma unroll
    for (int i = 0; i < 4; ++i)
        #pragma unroll
        for (int j = 0; j < 4; ++j) acc[i][j] = (f32x4){0.f, 0.f, 0.f, 0.f};

    #define PV_STAGE(buf, kt)                                                   \
        {                                                                       \
            const int kc = (kt) * 64;                                           \
            _Pragma("unroll")                                                   \
            for (int g = 0; g < 2; ++g) {                                       \
                const int r0 = w * 16 + g * 8, row = r0 + sr;                   \
                gload_lds16(A + (size_t)(rowbase + row) * 1024 + kc             \
                                + ((su ^ (row & 7)) << 3),                      \
                            &Alds[buf][r0][0]);                                 \
            }                                                                   \
            _Pragma("unroll")                                                   \
            for (int g = 0; g < 4; ++g) {                                       \
                const int r0 = w * 32 + g * 8, row = r0 + sr;                   \
                gload_lds16(wvb + (size_t)(colbase + row) * 1024 + kc           \
                                + ((su ^ (row & 7)) << 3),                      \
                            &Blds[buf][r0][0]);                                 \
            }                                                                   \
        }

    PV_STAGE(0, 0)
    __syncthreads();

    for (int kt = 0; kt < 16; ++kt) {
        const int cur = kt & 1;
        if (kt < 15) PV_STAGE(cur ^ 1, kt + 1)
        #pragma unroll
        for (int ks = 0; ks < 2; ++ks) {
            const int u = ((ks * 4 + lg) ^ (ll & 7)) * 8;
            bf16x8 af[4], bfr[4];
            #pragma unroll
            for (int mf = 0; mf < 4; ++mf)
                af[mf] = *(const bf16x8*)&Alds[cur][wr * 64 + mf * 16 + ll][u];
            #pragma unroll
            for (int nf = 0; nf < 4; ++nf)
                bfr[nf] = *(const bf16x8*)&Blds[cur][wc * 64 + nf * 16 + ll][u];
            #pragma unroll
            for (int mf = 0; mf < 4; ++mf)
                #pragma unroll
                for (int nf = 0; nf < 4; ++nf)
                    acc[mf][nf] = MFMA16(af[mf], bfr[nf], acc[mf][nf]);
        }
        __syncthreads();
    }
    #undef PV_STAGE

    float bvv[4];
    #pragma unroll
    for (int nf = 0; nf < 4; ++nf) bvv[nf] = bv[colbase + wc * 64 + nf * 16 + ll];

    if (mode == 0) {
        #pragma unroll
        for (int mf = 0; mf < 4; ++mf)
            #pragma unroll
            for (int r = 0; r < 4; ++r) {
                const size_t row = rowbase + wr * 64 + mf * 16 + lg * 4 + r;
                #pragma unroll
                for (int nf = 0; nf < 4; ++nf)
                    q_proto[row * 512 + colbase + wc * 64 + nf * 16 + ll] = acc[mf][nf][r] + bvv[nf];
            }
    } else {
        #pragma unroll
        for (int mf = 0; mf < 4; ++mf)
            #pragma unroll
            for (int nf = 0; nf < 4; ++nf) {
                float4_t pv = {acc[mf][nf][0] + bvv[nf], acc[mf][nf][1] + bvv[nf],
                               acc[mf][nf][2] + bvv[nf], acc[mf][nf][3] + bvv[nf]};
                const size_t col = colbase + wc * 64 + nf * 16 + ll;
                *(short4_t*)&VsT[col * 8192 + rowbase + wr * 64 + mf * 16 + lg * 4] = pack4(pv);
            }
    }
}

// ---------------------------------------------------------------------------
// proj_ln: dst = LN(in @ W^T + b), modes {0: support/Wk->Ks, 1: queries/Wq->Qs}.
// ---------------------------------------------------------------------------
__global__ __launch_bounds__(512, 2) void proj_ln_kernel(
    const unsigned short* __restrict__ sb, const unsigned short* __restrict__ qb,
    const unsigned short* __restrict__ wkb, const float* __restrict__ bk,
    const unsigned short* __restrict__ wqb, const float* __restrict__ bq,
    const float* __restrict__ gamma, const float* __restrict__ beta,
    unsigned short* __restrict__ Ks, unsigned short* __restrict__ Qs)
{
    const int mode = blockIdx.x >> 7;
    const int rowbase = (blockIdx.x & 127) * 64;
    const unsigned short* A = mode ? qb : sb;
    const unsigned short* W = mode ? wqb : wkb;
    const float* bias = mode ? bq : bk;
    unsigned short* dst = mode ? Qs : Ks;

    const int t = threadIdx.x;
    const int w = t >> 6, l = t & 63, lg = l >> 4, ll = l & 15;
    const int sr = l >> 3, su = l & 7;

    __shared__ unsigned short Alds[2][64][64];
    __shared__ unsigned short Blds[2][512][64];
    __shared__ float red[8][64][2];
    __shared__ float stats[64][2];

    f32x4 acc[4][4];
    #pragma unroll
    for (int i = 0; i < 4; ++i)
        #pragma unroll
        for (int j = 0; j < 4; ++j) acc[i][j] = (f32x4){0.f, 0.f, 0.f, 0.f};

    #define LN_STAGE(buf, kt)                                                   \
        {                                                                       \
            const int kc = (kt) * 64;                                           \
            {                                                                   \
                const int r0 = w * 8, row = r0 + sr;                            \
                gload_lds16(A + (size_t)(rowbase + row) * 1024 + kc             \
                                + ((su ^ (row & 7)) << 3),                      \
                            &Alds[buf][r0][0]);                                 \
            }                                                                   \
            _Pragma("unroll")                                                   \
            for (int g = 0; g < 8; ++g) {                                       \
                const int r0 = w * 64 + g * 8, row = r0 + sr;                   \
                gload_lds16(W + (size_t)row * 1024 + kc                         \
                                + ((su ^ (row & 7)) << 3),                      \
                            &Blds[buf][r0][0]);                                 \
            }                                                                   \
        }

    LN_STAGE(0, 0)
    __syncthreads();

    for (int kt = 0; kt < 16; ++kt) {
        const int cur = kt & 1;
        if (kt < 15) LN_STAGE(cur ^ 1, kt + 1)
        #pragma unroll
        for (int ks = 0; ks < 2; ++ks) {
            const int u = ((ks * 4 + lg) ^ (ll & 7)) * 8;
            bf16x8 af[4], bfr[4];
            #pragma unroll
            for (int mf = 0; mf < 4; ++mf)
                af[mf] = *(const bf16x8*)&Alds[cur][mf * 16 + ll][u];
            #pragma unroll
            for (int nf = 0; nf < 4; ++nf)
                bfr[nf] = *(const bf16x8*)&Blds[cur][w * 64 + nf * 16 + ll][u];
            #pragma unroll
            for (int mf = 0; mf < 4; ++mf)
                #pragma unroll
                for (int nf = 0; nf < 4; ++nf)
                    acc[mf][nf] = MFMA16(af[mf], bfr[nf], acc[mf][nf]);
        }
        __syncthreads();
    }
    #undef LN_STAGE

    float bvv[4];
    #pragma unroll
    for (int nf = 0; nf < 4; ++nf) bvv[nf] = bias[w * 64 + nf * 16 + ll];

    float v[4][4][4];
    #pragma unroll
    for (int mf = 0; mf < 4; ++mf)
        #pragma unroll
        for (int nf = 0; nf < 4; ++nf)
            #pragma unroll
            for (int r = 0; r < 4; ++r)
                v[mf][nf][r] = acc[mf][nf][r] + bvv[nf];

    #pragma unroll
    for (int mf = 0; mf < 4; ++mf)
        #pragma unroll
        for (int r = 0; r < 4; ++r) {
            float s = 0.f, q = 0.f;
            #pragma unroll
            for (int nf = 0; nf < 4; ++nf) { s += v[mf][nf][r]; q += v[mf][nf][r] * v[mf][nf][r]; }
            #pragma unroll
            for (int d = 1; d < 16; d <<= 1) { s += __shfl_xor(s, d); q += __shfl_xor(q, d); }
            if (ll == 0) {
                red[w][mf * 16 + lg * 4 + r][0] = s;
                red[w][mf * 16 + lg * 4 + r][1] = q;
            }
        }
    __syncthreads();
    if (t < 64) {
        float S = 0.f, Q = 0.f;
        #pragma unroll
        for (int w2 = 0; w2 < 8; ++w2) { S += red[w2][t][0]; Q += red[w2][t][1]; }
        const float mu = S * (1.f / 512.f);
        const float var = Q * (1.f / 512.f) - mu * mu;
        stats[t][0] = mu;
        stats[t][1] = rsqrtf(var + 1e-5f);
    }
    __syncthreads();
    float gv[4], bev[4];
    #pragma unroll
    for (int nf = 0; nf < 4; ++nf) {
        gv[nf] = gamma[w * 64 + nf * 16 + ll];
        bev[nf] = beta[w * 64 + nf * 16 + ll];
    }
    #pragma unroll
    for (int mf = 0; mf < 4; ++mf)
        #pragma unroll
        for (int r = 0; r < 4; ++r) {
            const int row = mf * 16 + lg * 4 + r;
            const float mu = stats[row][0], rs = stats[row][1];
            #pragma unroll
            for (int nf = 0; nf < 4; ++nf) {
                const float o = (v[mf][nf][r] - mu) * rs * gv[nf] + bev[nf];
                dst[(size_t)(rowbase + row) * 512 + w * 64 + nf * 16 + ll] = f2bf(o);
            }
        }
}

// ---------------------------------------------------------------------------
// Flash attention v8 = v4's proven phase structure + T4 counted vmcnt.
// BM=64, BKV=32, kv-split 2, grid 256, 8 waves, QK^T 4q x 2kv (qf[16]=64 VGPR,
// no spill), PV 1r x 8c. K QUAD-buffered (4 x 32KB, it&3), staged 2 tiles
// ahead; P double-buffered. Barriers via inline-asm s_waitcnt vmcnt(8)
// lgkmcnt(0) + s_barrier: the newest 8 VMEM ops (stage(it+2) 4 + vf(it) 4)
// stay in flight across the barrier; stage(it) is >=20 ops deep -> complete.
// Hazards: stage(n+2)->buf[(n+2)&3], last reader QKT(n-2), 2 barriers back.
// exp(n)->P[n&1], last reader PV(n-2), 2 barriers back. lgkmcnt(0) publishes
// P-writes. LDS: 128KB K + 8KB P + 0.5KB lsum.
// ---------------------------------------------------------------------------
__global__ __launch_bounds__(512, 2) void attn_kernel(
    const unsigned short* __restrict__ Qs, const unsigned short* __restrict__ Ks,
    const unsigned short* __restrict__ VsT,
    float* __restrict__ Opart, float* __restrict__ lpart)
{
    const int bid = blockIdx.x;
    const int sp = (bid & 7) >> 2;              // kv half pinned per XCD group
    const int qb = (bid >> 3) * 4 + (bid & 3);  // 0..127
    const int qbase = qb * 64;
    const int kv0 = sp * 4096;
    const int t = threadIdx.x;
    const int w = t >> 6, l = t & 63, lg = l >> 4, ll = l & 15;
    const int wq = w & 3, wk = w >> 2;          // QK^T: 4q x 2kv(16 each)

    __shared__ unsigned short Klds[4][32][512];   // 128 KB, src-preswizzled
    __shared__ unsigned short Plds[2][64][32];    // 8 KB, (row>>1)&3 swizzled
    __shared__ float lsum[2][64];

    bf16x8 qf[16];
    {
        const unsigned short* qrow = Qs + (size_t)(qbase + wq * 16 + ll) * 512 + lg * 8;
        #pragma unroll
        for (int ks = 0; ks < 16; ++ks)
            qf[ks] = *(const bf16x8*)(qrow + ks * 32);
    }

    f32x4 oacc[4][4];
    #pragma unroll
    for (int i = 0; i < 4; ++i)
        #pragma unroll
        for (int j = 0; j < 4; ++j) oacc[i][j] = (f32x4){0.f, 0.f, 0.f, 0.f};
    float lrun[4] = {0.f, 0.f, 0.f, 0.f};
    const float scale = 0.044194173824159216f;  // 1/sqrt(512)

    // stage one 32-row K tile: 4 rows per wave (row = w*4+rr)
    #define K_STAGE(buf, kvt)                                                   \
        {                                                                       \
            _Pragma("unroll")                                                   \
            for (int rr = 0; rr < 4; ++rr) {                                    \
                const int r = w * 4 + rr;                                       \
                gload_lds16(Ks + (size_t)((kvt) + r) * 512 + ((l ^ (r & 7)) << 3), \
                            &Klds[buf][r][0]);                                  \
            }                                                                   \
        }

    K_STAGE(0, kv0)
    K_STAGE(1, kv0 + 32)
    BARRIER_VM(4);   // tile0 complete (tile1's 4 loads stay in flight)

    for (int it = 0; it < 128; ++it) {
        const int cur = it & 3, pcur = it & 1;
        const int kvb = kv0 + it * 32;

        if (it < 126) K_STAGE((it + 2) & 3, kvb + 64)

        // V for PV(it): 4 global b128 per wave (issued early, consumed post-bar)
        bf16x8 vf[4];
        #pragma unroll
        for (int nf = 0; nf < 4; ++nf)
            vf[nf] = *(const bf16x8*)(VsT + (size_t)(w * 64 + nf * 16 + ll) * 8192
                                      + kvb + lg * 8);

        // QK^T: wave (wq,wk): q-rows wq*16..+16, kv-cols wk*16..+16
        f32x4 sacc = (f32x4){0.f, 0.f, 0.f, 0.f};
        __builtin_amdgcn_s_setprio(1);
        #pragma unroll
        for (int ks = 0; ks < 16; ++ks) {
            const int u = ((ks * 4 + lg) ^ (ll & 7)) * 8;
            bf16x8 kf = *(const bf16x8*)&Klds[cur][wk * 16 + ll][u];
            sacc = MFMA16(qf[ks], kf, sacc);
        }
        __builtin_amdgcn_s_setprio(0);

        // exp -> P[pcur]
        #pragma unroll
        for (int r = 0; r < 4; ++r) {
            const int row = wq * 16 + lg * 4 + r;
            const float p = __expf(sacc[r] * scale);
            const int col = wk * 16 + ll;
            const int unit = (col >> 3) ^ ((row >> 1) & 3);
            Plds[pcur][row][unit * 8 + (col & 7)] = f2bf(p);
            lrun[r] += p;
        }

        BARRIER_VM(8);   // P[pcur] visible; K(it) proven staged; 8 newest fly

        // PV: wave w owns out-cols w*64..+64, all 64 q-rows, K=32
        __builtin_amdgcn_s_setprio(1);
        #pragma unroll
        for (int mf = 0; mf < 4; ++mf) {
            const int row = mf * 16 + ll;
            const int unit = lg ^ ((row >> 1) & 3);
            bf16x8 pf = *(const bf16x8*)&Plds[pcur][row][unit * 8];
            #pragma unroll
            for (int nf = 0; nf < 4; ++nf)
                oacc[mf][nf] = MFMA16(pf, vf[nf], oacc[mf][nf]);
        }
        __builtin_amdgcn_s_setprio(0);
    }
    #undef K_STAGE

    const size_t obase = (size_t)sp * 8192 + qbase;
    #pragma unroll
    for (int mf = 0; mf < 4; ++mf)
        #pragma unroll
        for (int r = 0; r < 4; ++r) {
            const size_t row = obase + mf * 16 + lg * 4 + r;
            #pragma unroll
            for (int nf = 0; nf < 4; ++nf)
                Opart[row * 512 + w * 64 + nf * 16 + ll] = oacc[mf][nf][r];
        }

    // deferred softmax row-sum reduce (over the 16 ll lanes)
    #pragma unroll
    for (int r = 0; r < 4; ++r) {
        float val = lrun[r];
        #pragma unroll
        for (int d = 1; d < 16; d <<= 1) val += __shfl_xor(val, d);
        if (ll == 0)
            lsum[wk][wq * 16 + lg * 4 + r] = val;
    }
    __syncthreads();
    if (t < 64)
        lpart[(size_t)sp * 8192 + qbase + t] = lsum[0][t] + lsum[1][t];
}

// ---------------------------------------------------------------------------
// Merge: out2 = (sum_s Opart[s]) / (sum_s lpart[s]), s in {0,1}
// ---------------------------------------------------------------------------
__global__ __launch_bounds__(256) void merge_kernel(
    const float* __restrict__ Opart, const float* __restrict__ lpart,
    float* __restrict__ out2)
{
    const int idx = blockIdx.x * 256 + threadIdx.x;
    const int q = idx >> 7;
    const int c = (idx & 127) * 4;
    float4_t a = {0.f, 0.f, 0.f, 0.f};
    float ls = 0.f;
    #pragma unroll
    for (int s = 0; s < 2; ++s) {
        float4_t vv = *(const float4_t*)(Opart + ((size_t)s * 8192 + q) * 512 + c);
        a += vv;
        ls += lpart[s * 8192 + q];
    }
    const float inv = 1.f / ls;
    *(float4_t*)(out2 + (size_t)q * 512 + c) = a * inv;
}

extern "C" void kernel_launch(void* const* d_in, const int* in_sizes, int n_in,
                              void* d_out, int out_size, void* d_ws, size_t ws_size,
                              hipStream_t stream)
{
    const float* support = (const float*)d_in[0];
    const float* queries = (const float*)d_in[1];
    const float* Wq = (const float*)d_in[2];
    const float* bq = (const float*)d_in[3];
    const float* Wk = (const float*)d_in[4];
    const float* bk = (const float*)d_in[5];
    const float* Wv = (const float*)d_in[6];
    const float* bv = (const float*)d_in[7];
    const float* gamma = (const float*)d_in[8];
    const float* beta = (const float*)d_in[9];

    float* out = (float*)d_out;
    float* q_proto = out;                       // output 0: [8192,512]
    float* out2 = out + (size_t)8192 * 512;     // output 1: [8192,512]

    char* ws = (char*)d_ws;
    unsigned short* Qs  = (unsigned short*)(ws);                      //  0..8 MB
    unsigned short* Ks  = (unsigned short*)(ws + ((size_t)8 << 20));  //  8..16
    unsigned short* VsT = (unsigned short*)(ws + ((size_t)16 << 20)); // 16..24
    unsigned short* sb  = (unsigned short*)(ws + ((size_t)24 << 20)); // 24..40
    unsigned short* qbuf= (unsigned short*)(ws + ((size_t)40 << 20)); // 40..56
    unsigned short* wqb = (unsigned short*)(ws + ((size_t)56 << 20)); // 56..57
    unsigned short* wkb = (unsigned short*)(ws + ((size_t)57 << 20)); // 57..58
    unsigned short* wvb = (unsigned short*)(ws + ((size_t)58 << 20)); // 58..59
    // Opart aliases sb/qbuf (24..56 MB): proj kernels (sole readers of sb/qbuf)
    // complete before attn writes Opart; cast re-fills sb/qbuf every call.
    float* Opart = (float*)(ws + ((size_t)24 << 20));                 // 32 MB
    float* lpart = (float*)(ws + ((size_t)59 << 20));                 // 64 KB

    cast_kernel<<<8960, 256, 0, stream>>>(support, queries, Wq, Wk, Wv,
                                          sb, qbuf, wqb, wkb, wvb);
    proj_v_kernel<<<256, 512, 0, stream>>>(sb, qbuf, wvb, bv, q_proto, VsT);
    proj_ln_kernel<<<256, 512, 0, stream>>>(sb, qbuf, wkb, bk, wqb, bq,
                                            gamma, beta, Ks, Qs);
    attn_kernel<<<256, 512, 0, stream>>>(Qs, Ks, VsT, Opart, lpart);
    merge_kernel<<<4096, 256, 0, stream>>>(Opart, lpart, out2);
}